// Round 1
// baseline (1371.455 us; speedup 1.0000x reference)
//
#include <hip/hip_runtime.h>
#include <math.h>

#define NN     4
#define C1c    128
#define C2c    36
#define Hc     192
#define Wc     192
#define HOc    190
#define WOc    190
#define HWc    (Hc*Wc)        // 36864
#define CIG    32             // C1/GROUPS
#define CW_PAD 84             // 81 weights per input-channel row, padded to 16B multiple
#define LDS_FLOATS (C1c*CW_PAD)  // 10752 floats = 43008 B  -> 3 blocks/CU

__launch_bounds__(256, 2)
__global__ void dcn_fused(const float* __restrict__ x,
                          const float* __restrict__ conv_w,
                          const float* __restrict__ deform_w,
                          const float* __restrict__ bn_gamma,
                          const float* __restrict__ bn_beta,
                          const float* __restrict__ bn_mean,
                          const float* __restrict__ bn_var,
                          float* __restrict__ out) {
    __shared__ __align__(16) float lds[LDS_FLOATS];
    const int tid = threadIdx.x;
    const int n   = blockIdx.z;
    int wo = blockIdx.x * 64 + (tid & 63);
    int ho = blockIdx.y * 4  + (tid >> 6);
    const bool active = (wo < WOc) && (ho < HOc);
    if (wo > WOc - 1) wo = WOc - 1;   // clamp so inactive threads compute safely
    if (ho > HOc - 1) ho = HOc - 1;

    // ---- stage conv_w into padded LDS layout: row per input channel ch,
    //      row contents r = oo*9+tt  (oo = out-channel within group, tt = tap)
    for (int idx = tid; idx < C1c * 81; idx += 256) {
        int ch = idx / 81;
        int r  = idx - ch * 81;
        int g  = ch >> 5;
        int ci = ch & 31;
        int oo = r / 9;
        int tt = r - oo * 9;
        int o  = g * 9 + oo;
        lds[ch * CW_PAD + r] = conv_w[(o * CIG + ci) * 9 + tt];
    }
    __syncthreads();

    // ---- phase 1: offset-generating grouped conv (all 36 channels in regs)
    float offv[36];
    #pragma unroll
    for (int o = 0; o < 36; ++o) offv[o] = 0.f;

    const float* xn = x + (size_t)n * C1c * HWc;
    {
        const float* xp0 = xn + ho * Wc + wo;
        #pragma unroll
        for (int g = 0; g < 4; ++g) {
            #pragma unroll 1
            for (int ci = 0; ci < 32; ++ci) {
                const float* xp = xp0 + (g * 32 + ci) * HWc;
                float xv[9];
                #pragma unroll
                for (int i = 0; i < 3; ++i)
                    #pragma unroll
                    for (int j = 0; j < 3; ++j)
                        xv[i * 3 + j] = xp[i * Wc + j];
                const float* wr = &lds[(g * 32 + ci) * CW_PAD];
                #pragma unroll
                for (int oo = 0; oo < 9; ++oo) {
                    float a = offv[g * 9 + oo];
                    #pragma unroll
                    for (int tt = 0; tt < 9; ++tt)
                        a = fmaf(xv[tt], wr[oo * 9 + tt], a);
                    offv[g * 9 + oo] = a;
                }
            }
        }
    }

    // ---- phase 2: deformable sampling + 36-channel accumulation
    float acc[36];
    #pragma unroll
    for (int o = 0; o < 36; ++o) acc[o] = 0.f;

    #pragma unroll
    for (int t = 0; t < 9; ++t) {
        const int ki = t / 3, kj = t % 3;
        __syncthreads();   // previous lds readers done
        // stage W_t: lds[c*36 + o] = deform_w[(o*128+c)*9 + t]
        for (int idx = tid; idx < C1c * C2c; idx += 256) {
            int o = idx >> 7;
            int c = idx & 127;
            lds[c * 36 + o] = deform_w[(o * C1c + c) * 9 + t];
        }
        __syncthreads();

        // per-deformable-group bilinear corner data
        float cwt[2][4];
        int   cst[2][4];
        #pragma unroll
        for (int dg = 0; dg < 2; ++dg) {
            float dy = offv[dg * 18 + 2 * t];
            float dx = offv[dg * 18 + 2 * t + 1];
            float py = (float)(ho + ki) + dy;
            float px = (float)(wo + kj) + dx;
            float fy0 = floorf(py), fx0 = floorf(px);
            float wy = py - fy0, wx = px - fx0;
            float fy1 = fy0 + 1.f, fx1 = fx0 + 1.f;
            bool vy0 = (fy0 >= 0.f) && (fy0 <= (float)(Hc - 1));
            bool vy1 = (fy1 >= 0.f) && (fy1 <= (float)(Hc - 1));
            bool vx0 = (fx0 >= 0.f) && (fx0 <= (float)(Wc - 1));
            bool vx1 = (fx1 >= 0.f) && (fx1 <= (float)(Wc - 1));
            int iy0 = min(max((int)fy0, 0), Hc - 1);
            int iy1 = min(max((int)fy1, 0), Hc - 1);
            int ix0 = min(max((int)fx0, 0), Wc - 1);
            int ix1 = min(max((int)fx1, 0), Wc - 1);
            cwt[dg][0] = (vy0 && vx0) ? (1.f - wy) * (1.f - wx) : 0.f;
            cwt[dg][1] = (vy0 && vx1) ? (1.f - wy) * wx         : 0.f;
            cwt[dg][2] = (vy1 && vx0) ? wy * (1.f - wx)         : 0.f;
            cwt[dg][3] = (vy1 && vx1) ? wy * wx                 : 0.f;
            cst[dg][0] = iy0 * Wc + ix0;
            cst[dg][1] = iy0 * Wc + ix1;
            cst[dg][2] = iy1 * Wc + ix0;
            cst[dg][3] = iy1 * Wc + ix1;
        }

        #pragma unroll
        for (int hf = 0; hf < 2; ++hf) {   // hf == deformable group (c>>6)
            const float w0 = cwt[hf][0], w1 = cwt[hf][1], w2 = cwt[hf][2], w3 = cwt[hf][3];
            const int   s0 = cst[hf][0], s1 = cst[hf][1], s2 = cst[hf][2], s3 = cst[hf][3];
            const float* xp = xn + (size_t)(hf * 64) * HWc;
            const float4* wrow = (const float4*)&lds[hf * 64 * 36];
            #pragma unroll 2
            for (int c = 0; c < 64; ++c) {
                const float* xc = xp + (size_t)c * HWc;
                float v = w0 * xc[s0];
                v = fmaf(w1, xc[s1], v);
                v = fmaf(w2, xc[s2], v);
                v = fmaf(w3, xc[s3], v);
                #pragma unroll
                for (int ob = 0; ob < 9; ++ob) {
                    float4 q = wrow[c * 9 + ob];
                    acc[ob * 4 + 0] = fmaf(v, q.x, acc[ob * 4 + 0]);
                    acc[ob * 4 + 1] = fmaf(v, q.y, acc[ob * 4 + 1]);
                    acc[ob * 4 + 2] = fmaf(v, q.z, acc[ob * 4 + 2]);
                    acc[ob * 4 + 3] = fmaf(v, q.w, acc[ob * 4 + 3]);
                }
            }
        }
    }

    // ---- epilogue: BatchNorm (inference) + Mish
    if (active) {
        float* op = out + ((size_t)(n * C2c) * HOc + ho) * WOc + wo;
        #pragma unroll
        for (int o = 0; o < 36; ++o) {
            float inv = bn_gamma[o] * rsqrtf(bn_var[o] + 1e-5f);
            float b   = bn_beta[o] - bn_mean[o] * inv;
            float v   = fmaf(acc[o], inv, b);
            float sp  = (v > 20.f) ? v : log1pf(__expf(v));
            float e2  = __expf(-2.f * sp);
            float th  = (1.f - e2) / (1.f + e2);
            op[(size_t)o * HOc * WOc] = v * th;
        }
    }
}

extern "C" void kernel_launch(void* const* d_in, const int* in_sizes, int n_in,
                              void* d_out, int out_size, void* d_ws, size_t ws_size,
                              hipStream_t stream) {
    const float* x        = (const float*)d_in[0];
    const float* conv_w   = (const float*)d_in[1];
    const float* deform_w = (const float*)d_in[2];
    const float* bn_gamma = (const float*)d_in[3];
    const float* bn_beta  = (const float*)d_in[4];
    const float* bn_mean  = (const float*)d_in[5];
    const float* bn_var   = (const float*)d_in[6];
    float* out = (float*)d_out;

    dim3 block(256, 1, 1);
    dim3 grid((WOc + 63) / 64, (HOc + 3) / 4, NN);  // 3 x 48 x 4 = 576 blocks
    dcn_fused<<<grid, block, 0, stream>>>(x, conv_w, deform_w,
                                          bn_gamma, bn_beta, bn_mean, bn_var, out);
}

// Round 2
// 1368.347 us; speedup vs baseline: 1.0023x; 1.0023x over previous
//
#include <hip/hip_runtime.h>
#include <math.h>

#define NN     4
#define C1c    128
#define C2c    36
#define Hc     192
#define Wc     192
#define HOc    190
#define WOc    190
#define HWc    (Hc*Wc)        // 36864
#define HWO    (HOc*WOc)      // 36100
#define CIG    32             // C1/GROUPS
#define CW_PAD 84             // 81 weights per input-channel row, padded to 16B multiple
#define LDS_FLOATS (C1c*CW_PAD)

// ---------------- kernel T: transpose deform_w -> wT[t][c][o] (o contiguous) ----
__global__ void transpose_w(const float* __restrict__ dw, float* __restrict__ wT) {
    int d = blockIdx.x * 256 + threadIdx.x;
    if (d >= 9 * 128 * 36) return;
    int o = d % 36;
    int r = d / 36;
    int c = r % 128;
    int t = r / 128;
    wT[d] = dw[(o * 128 + c) * 9 + t];
}

// ---------------- kernel A: offset-generating grouped conv -> offs[n][36][HO][WO]
__launch_bounds__(256, 2)
__global__ void dcn_offsets(const float* __restrict__ x,
                            const float* __restrict__ conv_w,
                            float* __restrict__ offs) {
    __shared__ __align__(16) float lds[LDS_FLOATS];
    const int tid = threadIdx.x;
    const int n   = blockIdx.z;
    int wo = blockIdx.x * 64 + (tid & 63);
    int ho = blockIdx.y * 4  + (tid >> 6);
    const bool active = (wo < WOc) && (ho < HOc);
    if (wo > WOc - 1) wo = WOc - 1;
    if (ho > HOc - 1) ho = HOc - 1;

    for (int idx = tid; idx < C1c * 81; idx += 256) {
        int ch = idx / 81;
        int r  = idx - ch * 81;
        int g  = ch >> 5;
        int ci = ch & 31;
        int oo = r / 9;
        int tt = r - oo * 9;
        int o  = g * 9 + oo;
        lds[ch * CW_PAD + r] = conv_w[(o * CIG + ci) * 9 + tt];
    }
    __syncthreads();

    float offv[36];
    #pragma unroll
    for (int o = 0; o < 36; ++o) offv[o] = 0.f;

    const float* xn  = x + (size_t)n * C1c * HWc;
    const float* xp0 = xn + ho * Wc + wo;
    #pragma unroll
    for (int g = 0; g < 4; ++g) {
        #pragma unroll 1
        for (int ci = 0; ci < 32; ++ci) {
            const float* xp = xp0 + (g * 32 + ci) * HWc;
            float xv[9];
            #pragma unroll
            for (int i = 0; i < 3; ++i)
                #pragma unroll
                for (int j = 0; j < 3; ++j)
                    xv[i * 3 + j] = xp[i * Wc + j];
            const float* wr = &lds[(g * 32 + ci) * CW_PAD];
            #pragma unroll
            for (int oo = 0; oo < 9; ++oo) {
                float a = offv[g * 9 + oo];
                #pragma unroll
                for (int tt = 0; tt < 9; ++tt)
                    a = fmaf(xv[tt], wr[oo * 9 + tt], a);
                offv[g * 9 + oo] = a;
            }
        }
    }

    if (active) {
        float* op = offs + (((size_t)n * 36) * HOc + ho) * WOc + wo;
        #pragma unroll
        for (int o = 0; o < 36; ++o)
            op[(size_t)o * HWO] = offv[o];
    }
}

// ---------------- kernel B: deformable sampling + 12-channel reduction + BN/Mish
__launch_bounds__(256, 4)
__global__ void dcn_sample(const float* __restrict__ x,
                           const float* __restrict__ wT,
                           const float* __restrict__ offs,
                           const float* __restrict__ bn_gamma,
                           const float* __restrict__ bn_beta,
                           const float* __restrict__ bn_mean,
                           const float* __restrict__ bn_var,
                           float* __restrict__ out) {
    const int tid = threadIdx.x;
    // XCD-aware decode: the 3 o-splits of one spatial tile share an XCD,
    // and each XCD gets 72 contiguous spatial tiles (L2 locality).
    const int id      = blockIdx.x;          // [0, 1728)
    const int xcd     = id & 7;
    const int slot    = id >> 3;             // [0, 216)
    const int spatial = xcd * 72 + slot / 3; // [0, 576)
    const int osplit  = slot % 3;
    const int obase   = osplit * 12;

    const int n   = spatial / 144;
    int rem       = spatial - n * 144;
    const int tyl = rem / 3;
    const int txl = rem - tyl * 3;
    int wo = txl * 64 + (tid & 63);
    int ho = tyl * 4  + (tid >> 6);
    const bool active = (wo < WOc) && (ho < HOc);
    if (wo > WOc - 1) wo = WOc - 1;
    if (ho > HOc - 1) ho = HOc - 1;

    const float* xn   = x + (size_t)n * C1c * HWc;
    const float* offp = offs + ((size_t)n * 36 * HWO) + (size_t)ho * WOc + wo;

    float acc[12];
    #pragma unroll
    for (int j = 0; j < 12; ++j) acc[j] = 0.f;

    #pragma unroll 1
    for (int t = 0; t < 9; ++t) {
        const int ki = t / 3, kj = t - ki * 3;

        float cwt[2][4];
        int   cst[2][4];
        #pragma unroll
        for (int dg = 0; dg < 2; ++dg) {
            float dy = offp[(size_t)(dg * 18 + 2 * t + 0) * HWO];
            float dx = offp[(size_t)(dg * 18 + 2 * t + 1) * HWO];
            float py = (float)(ho + ki) + dy;
            float px = (float)(wo + kj) + dx;
            float fy0 = floorf(py), fx0 = floorf(px);
            float wy = py - fy0, wx = px - fx0;
            float fy1 = fy0 + 1.f, fx1 = fx0 + 1.f;
            bool vy0 = (fy0 >= 0.f) && (fy0 <= (float)(Hc - 1));
            bool vy1 = (fy1 >= 0.f) && (fy1 <= (float)(Hc - 1));
            bool vx0 = (fx0 >= 0.f) && (fx0 <= (float)(Wc - 1));
            bool vx1 = (fx1 >= 0.f) && (fx1 <= (float)(Wc - 1));
            int iy0 = min(max((int)fy0, 0), Hc - 1);
            int iy1 = min(max((int)fy1, 0), Hc - 1);
            int ix0 = min(max((int)fx0, 0), Wc - 1);
            int ix1 = min(max((int)fx1, 0), Wc - 1);
            cwt[dg][0] = (vy0 && vx0) ? (1.f - wy) * (1.f - wx) : 0.f;
            cwt[dg][1] = (vy0 && vx1) ? (1.f - wy) * wx         : 0.f;
            cwt[dg][2] = (vy1 && vx0) ? wy * (1.f - wx)         : 0.f;
            cwt[dg][3] = (vy1 && vx1) ? wy * wx                 : 0.f;
            cst[dg][0] = iy0 * Wc + ix0;
            cst[dg][1] = iy0 * Wc + ix1;
            cst[dg][2] = iy1 * Wc + ix0;
            cst[dg][3] = iy1 * Wc + ix1;
        }

        #pragma unroll
        for (int hf = 0; hf < 2; ++hf) {
            const float w0 = cwt[hf][0], w1 = cwt[hf][1], w2 = cwt[hf][2], w3 = cwt[hf][3];
            const int   s0 = cst[hf][0], s1 = cst[hf][1], s2 = cst[hf][2], s3 = cst[hf][3];
            const float* xp = xn + (size_t)(hf * 64) * HWc;
            // wave-uniform weight rows (16B aligned: obase*4 and row*144 are both /16)
            const float* wb = wT + (size_t)(t * 128 + hf * 64) * 36 + obase;
            #pragma unroll 2
            for (int c = 0; c < 64; ++c) {
                const float* xc = xp + (size_t)c * HWc;
                float v = w0 * xc[s0];
                v = fmaf(w1, xc[s1], v);
                v = fmaf(w2, xc[s2], v);
                v = fmaf(w3, xc[s3], v);
                const float4* wr = (const float4*)(wb + (size_t)c * 36);
                float4 q0 = wr[0];
                float4 q1 = wr[1];
                float4 q2 = wr[2];
                acc[0]  = fmaf(v, q0.x, acc[0]);
                acc[1]  = fmaf(v, q0.y, acc[1]);
                acc[2]  = fmaf(v, q0.z, acc[2]);
                acc[3]  = fmaf(v, q0.w, acc[3]);
                acc[4]  = fmaf(v, q1.x, acc[4]);
                acc[5]  = fmaf(v, q1.y, acc[5]);
                acc[6]  = fmaf(v, q1.z, acc[6]);
                acc[7]  = fmaf(v, q1.w, acc[7]);
                acc[8]  = fmaf(v, q2.x, acc[8]);
                acc[9]  = fmaf(v, q2.y, acc[9]);
                acc[10] = fmaf(v, q2.z, acc[10]);
                acc[11] = fmaf(v, q2.w, acc[11]);
            }
        }
    }

    if (active) {
        float* op = out + (((size_t)n * 36 + obase) * HOc + ho) * WOc + wo;
        #pragma unroll
        for (int j = 0; j < 12; ++j) {
            int o = obase + j;
            float inv = bn_gamma[o] * rsqrtf(bn_var[o] + 1e-5f);
            float b   = bn_beta[o] - bn_mean[o] * inv;
            float v   = fmaf(acc[j], inv, b);
            float sp  = (v > 20.f) ? v : log1pf(__expf(v));
            float e2  = __expf(-2.f * sp);
            float th  = (1.f - e2) / (1.f + e2);
            op[(size_t)j * HWO] = v * th;
        }
    }
}

extern "C" void kernel_launch(void* const* d_in, const int* in_sizes, int n_in,
                              void* d_out, int out_size, void* d_ws, size_t ws_size,
                              hipStream_t stream) {
    (void)in_sizes; (void)n_in; (void)out_size; (void)ws_size;
    const float* x        = (const float*)d_in[0];
    const float* conv_w   = (const float*)d_in[1];
    const float* deform_w = (const float*)d_in[2];
    const float* bn_gamma = (const float*)d_in[3];
    const float* bn_beta  = (const float*)d_in[4];
    const float* bn_mean  = (const float*)d_in[5];
    const float* bn_var   = (const float*)d_in[6];
    float* out = (float*)d_out;

    float* offs = (float*)d_ws;                         // 4*36*36100 floats = 20.8 MB
    float* wTp  = offs + (size_t)NN * 36 * HWO;         // 9*128*36 floats = 166 KB

    transpose_w<<<162, 256, 0, stream>>>(deform_w, wTp);
    dcn_offsets<<<dim3(3, 48, 4), 256, 0, stream>>>(x, conv_w, offs);
    dcn_sample<<<1728, 256, 0, stream>>>(x, wTp, offs,
                                         bn_gamma, bn_beta, bn_mean, bn_var, out);
}

// Round 3
// 812.523 us; speedup vs baseline: 1.6879x; 1.6841x over previous
//
#include <hip/hip_runtime.h>
#include <hip/hip_bf16.h>
#include <math.h>

#define NN     4
#define C1c    128
#define C2c    36
#define Hc     192
#define Wc     192
#define HOc    190
#define WOc    190
#define HWc    (Hc*Wc)        // 36864
#define HWO    (HOc*WOc)      // 36100
#define SPITCH 136            // shorts per S row: 128 + 8 pad (272 B)

using v8s = __attribute__((ext_vector_type(8))) short;
using v4f = __attribute__((ext_vector_type(4))) float;

__device__ __forceinline__ unsigned short f2bf(float f) {
    __hip_bfloat16 h = __float2bfloat16(f);
    return __builtin_bit_cast(unsigned short, h);
}
__device__ __forceinline__ float bf2f(unsigned short u) {
    __hip_bfloat16 h = __builtin_bit_cast(__hip_bfloat16, u);
    return __bfloat162float(h);
}

// ---------------- x: NCHW fp32 -> NHWC bf16 ------------------------------
__global__ void x_to_nhwc(const float* __restrict__ x, unsigned short* __restrict__ xt) {
    __shared__ float tile[64 * 129];
    const int tid = threadIdx.x;
    const int w0  = blockIdx.x * 64;
    const int h   = blockIdx.y;
    const int n   = blockIdx.z;
    {
        const int w  = tid & 63, cb = tid >> 6;
        const float* xp = x + ((size_t)n * C1c * Hc + h) * Wc + w0 + w;
        #pragma unroll
        for (int i = 0; i < 32; ++i) {
            int c = cb + i * 4;
            tile[w * 129 + c] = xp[(size_t)c * HWc];
        }
    }
    __syncthreads();
    {
        const int c2 = tid & 127, wb2 = tid >> 7;
        unsigned short* op = xt + ((size_t)((n * Hc + h) * Wc) + w0) * C1c + c2;
        #pragma unroll
        for (int j = 0; j < 32; ++j) {
            int ww = wb2 + j * 2;
            op[(size_t)ww * C1c] = f2bf(tile[ww * 129 + c2]);
        }
    }
}

// ---------------- deform_w -> bf16 wb[t][48][128] (o rows 36..47 zero) ----
__global__ void w_prep(const float* __restrict__ dw, unsigned short* __restrict__ wb) {
    int i = blockIdx.x * 256 + threadIdx.x;
    if (i >= 9 * 48 * 128) return;
    int c = i & 127;
    int r = i >> 7;           // t*48 + o
    int o = r % 48, t = r / 48;
    float v = (o < 36) ? dw[((size_t)o * C1c + c) * 9 + t] : 0.f;
    wb[i] = f2bf(v);
}

// ---------------- offset-generating grouped conv (o-split x2) -------------
#define CW_PAD 84
__launch_bounds__(256, 4)
__global__ void dcn_offsets(const float* __restrict__ x,
                            const float* __restrict__ conv_w,
                            float* __restrict__ offs) {
    __shared__ __align__(16) float lds[64 * CW_PAD];   // 21504 B
    const int tid  = threadIdx.x;
    const int n    = blockIdx.z >> 1;
    const int half = blockIdx.z & 1;
    int wo = blockIdx.x * 64 + (tid & 63);
    int ho = blockIdx.y * 4  + (tid >> 6);
    const bool active = (wo < WOc) && (ho < HOc);
    if (wo > WOc - 1) wo = WOc - 1;
    if (ho > HOc - 1) ho = HOc - 1;

    for (int idx = tid; idx < 64 * 81; idx += 256) {
        int ch = idx / 81;             // local channel 0..63
        int r  = idx - ch * 81;
        int gl = ch >> 5;              // local group 0..1
        int ci = ch & 31;
        int oo = r / 9;
        int tt = r - oo * 9;
        int o  = (half * 2 + gl) * 9 + oo;
        lds[ch * CW_PAD + r] = conv_w[(o * 32 + ci) * 9 + tt];
    }
    __syncthreads();

    float offv[18];
    #pragma unroll
    for (int o = 0; o < 18; ++o) offv[o] = 0.f;

    const float* xn  = x + (size_t)n * C1c * HWc;
    const float* xp0 = xn + ho * Wc + wo;
    #pragma unroll
    for (int gl = 0; gl < 2; ++gl) {
        #pragma unroll 1
        for (int ci = 0; ci < 32; ++ci) {
            const float* xp = xp0 + ((half * 2 + gl) * 32 + ci) * HWc;
            float xv[9];
            #pragma unroll
            for (int i = 0; i < 3; ++i)
                #pragma unroll
                for (int j = 0; j < 3; ++j)
                    xv[i * 3 + j] = xp[i * Wc + j];
            const float* wr = &lds[(gl * 32 + ci) * CW_PAD];
            #pragma unroll
            for (int oo = 0; oo < 9; ++oo) {
                float a = offv[gl * 9 + oo];
                #pragma unroll
                for (int tt = 0; tt < 9; ++tt)
                    a = fmaf(xv[tt], wr[oo * 9 + tt], a);
                offv[gl * 9 + oo] = a;
            }
        }
    }

    if (active) {
        float* op = offs + ((size_t)n * 36 + half * 18) * HWO + (size_t)ho * WOc + wo;
        #pragma unroll
        for (int o = 0; o < 18; ++o)
            op[(size_t)o * HWO] = offv[o];
    }
}

// ---------------- main: sampling + MFMA reduction + BN/Mish ---------------
__launch_bounds__(256, 4)
__global__ void dcn_mfma(const unsigned short* __restrict__ xt,
                         const unsigned short* __restrict__ wb,
                         const float* __restrict__ offs,
                         const float* __restrict__ bn_gamma,
                         const float* __restrict__ bn_beta,
                         const float* __restrict__ bn_mean,
                         const float* __restrict__ bn_var,
                         float* __restrict__ out) {
    __shared__ __align__(16) unsigned short S[4 * 16 * SPITCH];  // 17408 B
    const int tid  = threadIdx.x;
    const int lane = tid & 63;
    const int wave = tid >> 6;
    const int n    = blockIdx.y;
    const int pxb  = blockIdx.x * 64 + wave * 16;    // spatial base for this wave
    unsigned short* Sw = S + wave * 16 * SPITCH;

    // precompute-lane identity: lanes 0..31 -> (pi = lane&15, dg = lane>>4)
    const int pi  = lane & 15;
    const int dgl = (lane >> 4) & 1;
    int pxs = pxb + pi;
    if (pxs > HWO - 1) pxs = HWO - 1;
    const int ho = pxs / 190;
    const int wo = pxs - ho * 190;
    const float* offp = offs + (size_t)n * 36 * HWO;
    const unsigned short* xb = xt + (size_t)n * HWc * C1c;

    v4f acc[3];
    #pragma unroll
    for (int i = 0; i < 3; ++i) acc[i] = (v4f){0.f, 0.f, 0.f, 0.f};

    #pragma unroll 1
    for (int t = 0; t < 9; ++t) {
        const int ki = t / 3, kj = t - ki * 3;

        // ---- corner data for (pi, dgl) in each of lanes 0..31 (32..63 dup)
        float dy = offp[(size_t)(dgl * 18 + 2 * t + 0) * HWO + pxs];
        float dx = offp[(size_t)(dgl * 18 + 2 * t + 1) * HWO + pxs];
        float py  = (float)(ho + ki) + dy;
        float pxf = (float)(wo + kj) + dx;
        float fy0 = floorf(py), fx0 = floorf(pxf);
        float wy = py - fy0, wx = pxf - fx0;
        float fy1 = fy0 + 1.f, fx1 = fx0 + 1.f;
        bool vy0 = (fy0 >= 0.f) && (fy0 <= (float)(Hc - 1));
        bool vy1 = (fy1 >= 0.f) && (fy1 <= (float)(Hc - 1));
        bool vx0 = (fx0 >= 0.f) && (fx0 <= (float)(Wc - 1));
        bool vx1 = (fx1 >= 0.f) && (fx1 <= (float)(Wc - 1));
        int iy0 = min(max((int)fy0, 0), Hc - 1);
        int iy1 = min(max((int)fy1, 0), Hc - 1);
        int ix0 = min(max((int)fx0, 0), Wc - 1);
        int ix1 = min(max((int)fx1, 0), Wc - 1);
        float w00v = (vy0 && vx0) ? (1.f - wy) * (1.f - wx) : 0.f;
        float w01v = (vy0 && vx1) ? (1.f - wy) * wx         : 0.f;
        float w10v = (vy1 && vx0) ? wy * (1.f - wx)         : 0.f;
        float w11v = (vy1 && vx1) ? wy * wx                 : 0.f;
        int c00v = iy0 * Wc + ix0;
        int c01v = iy0 * Wc + ix1;
        int c10v = iy1 * Wc + ix0;
        int c11v = iy1 * Wc + ix1;

        // ---- sampling: 16 px x 2 dg steps, lane = channel within dg
        #pragma unroll
        for (int p = 0; p < 16; ++p) {
            #pragma unroll
            for (int dg = 0; dg < 2; ++dg) {
                const int src = dg * 16 + p;
                const float w00 = __int_as_float(__builtin_amdgcn_readlane(__float_as_int(w00v), src));
                const float w01 = __int_as_float(__builtin_amdgcn_readlane(__float_as_int(w01v), src));
                const float w10 = __int_as_float(__builtin_amdgcn_readlane(__float_as_int(w10v), src));
                const float w11 = __int_as_float(__builtin_amdgcn_readlane(__float_as_int(w11v), src));
                const int   c00 = __builtin_amdgcn_readlane(c00v, src);
                const int   c01 = __builtin_amdgcn_readlane(c01v, src);
                const int   c10 = __builtin_amdgcn_readlane(c10v, src);
                const int   c11 = __builtin_amdgcn_readlane(c11v, src);
                const unsigned short* bp = xb + dg * 64 + lane;
                float v00 = bf2f(bp[(size_t)c00 * C1c]);
                float v01 = bf2f(bp[(size_t)c01 * C1c]);
                float v10 = bf2f(bp[(size_t)c10 * C1c]);
                float v11 = bf2f(bp[(size_t)c11 * C1c]);
                float v = fmaf(w11, v11, fmaf(w10, v10, fmaf(w01, v01, w00 * v00)));
                Sw[p * SPITCH + dg * 64 + lane] = f2bf(v);
            }
        }

        // ---- MFMA: D[o][px] += W_t[o][k] * S[k][px], K=128 in 4 steps
        const unsigned short* wt = wb + ((size_t)t * 48 + (lane & 15)) * C1c + ((lane >> 4) & 3) * 8;
        const unsigned short* sb = Sw + (lane & 15) * SPITCH + ((lane >> 4) & 3) * 8;
        #pragma unroll
        for (int ks = 0; ks < 4; ++ks) {
            v8s bfrag = *(const v8s*)(sb + ks * 32);
            v8s a0 = *(const v8s*)(wt + ks * 32);
            v8s a1 = *(const v8s*)(wt + 16 * C1c + ks * 32);
            v8s a2 = *(const v8s*)(wt + 32 * C1c + ks * 32);
            acc[0] = __builtin_amdgcn_mfma_f32_16x16x32_bf16(a0, bfrag, acc[0], 0, 0, 0);
            acc[1] = __builtin_amdgcn_mfma_f32_16x16x32_bf16(a1, bfrag, acc[1], 0, 0, 0);
            acc[2] = __builtin_amdgcn_mfma_f32_16x16x32_bf16(a2, bfrag, acc[2], 0, 0, 0);
        }
    }

    // ---- epilogue: BN + Mish; C layout col=lane&15 (px), row=quad*4+reg (o)
    const int col  = lane & 15;
    const int rowq = ((lane >> 4) & 3) * 4;
    const int pxo  = pxb + col;
    if (pxo < HWO) {
        #pragma unroll
        for (int ot = 0; ot < 3; ++ot) {
            #pragma unroll
            for (int r = 0; r < 4; ++r) {
                int o = ot * 16 + rowq + r;
                if (o < 36) {
                    float inv = bn_gamma[o] * rsqrtf(bn_var[o] + 1e-5f);
                    float b   = bn_beta[o] - bn_mean[o] * inv;
                    float v   = fmaf(acc[ot][r], inv, b);
                    float sp  = (v > 20.f) ? v : log1pf(__expf(v));
                    float e2  = __expf(-2.f * sp);
                    float th  = (1.f - e2) / (1.f + e2);
                    out[((size_t)n * 36 + o) * HWO + pxo] = v * th;
                }
            }
        }
    }
}

extern "C" void kernel_launch(void* const* d_in, const int* in_sizes, int n_in,
                              void* d_out, int out_size, void* d_ws, size_t ws_size,
                              hipStream_t stream) {
    (void)in_sizes; (void)n_in; (void)out_size; (void)ws_size;
    const float* x        = (const float*)d_in[0];
    const float* conv_w   = (const float*)d_in[1];
    const float* deform_w = (const float*)d_in[2];
    const float* bn_gamma = (const float*)d_in[3];
    const float* bn_beta  = (const float*)d_in[4];
    const float* bn_mean  = (const float*)d_in[5];
    const float* bn_var   = (const float*)d_in[6];
    float* out = (float*)d_out;

    float*          offs = (float*)d_ws;                          // 20.8 MB
    unsigned short* xt   = (unsigned short*)(offs + (size_t)NN * 36 * HWO);  // 37.7 MB
    unsigned short* wbp  = xt + (size_t)NN * HWc * C1c;           // 110.6 KB

    x_to_nhwc<<<dim3(3, 192, 4), 256, 0, stream>>>(x, xt);
    w_prep<<<216, 256, 0, stream>>>(deform_w, wbp);
    dcn_offsets<<<dim3(3, 48, 8), 256, 0, stream>>>(x, conv_w, offs);
    dcn_mfma<<<dim3(565, 4), 256, 0, stream>>>(xt, wbp, offs,
                                               bn_gamma, bn_beta, bn_mean, bn_var, out);
}

// Round 4
// 449.650 us; speedup vs baseline: 3.0501x; 1.8070x over previous
//
#include <hip/hip_runtime.h>
#include <hip/hip_bf16.h>
#include <math.h>

#define NN     4
#define C1c    128
#define C2c    36
#define Hc     192
#define Wc     192
#define HOc    190
#define WOc    190
#define HWc    (Hc*Wc)        // 36864
#define HWO    (HOc*WOc)      // 36100
#define SPITCH 136            // shorts per S row: 128 + 8 pad (272 B)

using v8s = __attribute__((ext_vector_type(8))) short;
using v4f = __attribute__((ext_vector_type(4))) float;

__device__ __forceinline__ unsigned short f2bf(float f) {
    __hip_bfloat16 h = __float2bfloat16(f);
    return __builtin_bit_cast(unsigned short, h);
}
__device__ __forceinline__ float bf2f(unsigned short u) {
    __hip_bfloat16 h = __builtin_bit_cast(__hip_bfloat16, u);
    return __bfloat162float(h);
}
__device__ __forceinline__ float rlanef(float v, int src) {
    return __int_as_float(__builtin_amdgcn_readlane(__float_as_int(v), src));
}

// ---------------- x: NCHW fp32 -> NHWC bf16 ------------------------------
__global__ void x_to_nhwc(const float* __restrict__ x, unsigned short* __restrict__ xt) {
    __shared__ float tile[64 * 129];
    const int tid = threadIdx.x;
    const int w0  = blockIdx.x * 64;
    const int h   = blockIdx.y;
    const int n   = blockIdx.z;
    {
        const int w  = tid & 63, cb = tid >> 6;
        const float* xp = x + ((size_t)n * C1c * Hc + h) * Wc + w0 + w;
        #pragma unroll
        for (int i = 0; i < 32; ++i) {
            int c = cb + i * 4;
            tile[w * 129 + c] = xp[(size_t)c * HWc];
        }
    }
    __syncthreads();
    {
        const int c2 = tid & 127, wb2 = tid >> 7;
        unsigned short* op = xt + ((size_t)((n * Hc + h) * Wc) + w0) * C1c + c2;
        #pragma unroll
        for (int j = 0; j < 32; ++j) {
            int ww = wb2 + j * 2;
            op[(size_t)ww * C1c] = f2bf(tile[ww * 129 + c2]);
        }
    }
}

// ---------------- deform_w -> bf16 wb[t][48][128] (o rows 36..47 zero) ----
__global__ void w_prep(const float* __restrict__ dw, unsigned short* __restrict__ wb) {
    int i = blockIdx.x * 256 + threadIdx.x;
    if (i >= 9 * 48 * 128) return;
    int c = i & 127;
    int r = i >> 7;           // t*48 + o
    int o = r % 48, t = r / 48;
    float v = (o < 36) ? dw[((size_t)o * C1c + c) * 9 + t] : 0.f;
    wb[i] = f2bf(v);
}

// ---------------- conv_w -> cwT[(g*32+ci)*84 + oo*9+tt] (rows padded) -----
__global__ void cw_prep(const float* __restrict__ cw, float* __restrict__ cwT) {
    int i = blockIdx.x * 256 + threadIdx.x;
    if (i >= 4 * 32 * 84) return;
    int r   = i / 84;          // g*32+ci
    int idx = i - r * 84;
    int g = r >> 5, ci = r & 31;
    float v = 0.f;
    if (idx < 81) {
        int oo = idx / 9, tt = idx - oo * 9;
        int o  = g * 9 + oo;
        v = cw[(o * 32 + ci) * 9 + tt];
    }
    cwT[i] = v;
}

// ---------------- offset conv: weights via scalar K$ broadcast ------------
__launch_bounds__(256, 8)
__global__ void dcn_offsets(const float* __restrict__ x,
                            const float* __restrict__ cwT,
                            float* __restrict__ offs) {
    const int tid = threadIdx.x;
    const int n   = blockIdx.z >> 2;
    const int g   = blockIdx.z & 3;
    int wo = blockIdx.x * 64 + (tid & 63);
    int ho = blockIdx.y * 4  + (tid >> 6);
    const bool active = (wo < WOc) && (ho < HOc);
    if (wo > WOc - 1) wo = WOc - 1;
    if (ho > HOc - 1) ho = HOc - 1;

    float offv[9];
    #pragma unroll
    for (int oo = 0; oo < 9; ++oo) offv[oo] = 0.f;

    const float* xp0 = x + ((size_t)n * C1c + g * 32) * HWc + ho * Wc + wo;
    const float* wr0 = cwT + (size_t)g * 32 * 84;
    #pragma unroll 1
    for (int ci = 0; ci < 32; ++ci) {
        const float* xp = xp0 + (size_t)ci * HWc;
        float xv[9];
        #pragma unroll
        for (int i = 0; i < 3; ++i)
            #pragma unroll
            for (int j = 0; j < 3; ++j)
                xv[i * 3 + j] = xp[i * Wc + j];
        const float* wr = wr0 + ci * 84;   // wave-uniform -> s_load
        #pragma unroll
        for (int oo = 0; oo < 9; ++oo) {
            float a = offv[oo];
            #pragma unroll
            for (int tt = 0; tt < 9; ++tt)
                a = fmaf(xv[tt], wr[oo * 9 + tt], a);
            offv[oo] = a;
        }
    }

    if (active) {
        float* op = offs + ((size_t)n * 36 + g * 9) * HWO + (size_t)ho * WOc + wo;
        #pragma unroll
        for (int oo = 0; oo < 9; ++oo)
            op[(size_t)oo * HWO] = offv[oo];
    }
}

// ---------------- main: sampling + MFMA reduction + BN/Mish ---------------
__launch_bounds__(256, 6)
__global__ void dcn_mfma(const unsigned short* __restrict__ xt,
                         const unsigned short* __restrict__ wb,
                         const float* __restrict__ offs,
                         const float* __restrict__ bn_gamma,
                         const float* __restrict__ bn_beta,
                         const float* __restrict__ bn_mean,
                         const float* __restrict__ bn_var,
                         float* __restrict__ out) {
    __shared__ __align__(16) unsigned short S[4 * 16 * SPITCH];  // 17408 B
    const int tid  = threadIdx.x;
    const int lane = tid & 63;
    const int wave = tid >> 6;

    // XCD-contiguous decode: each XCD owns 283 consecutive (n,strip) slots.
    int gs = (blockIdx.x & 7) * 283 + (blockIdx.x >> 3);
    if (gs > NN * 565 - 1) gs = NN * 565 - 1;
    const int n     = gs / 565;
    const int strip = gs - n * 565;
    const int pxb   = strip * 64 + wave * 16;
    unsigned short* Sw = S + wave * 16 * SPITCH;

    const int pi  = lane & 15;
    const int dgl = (lane >> 4) & 1;
    int pxs = pxb + pi;
    if (pxs > HWO - 1) pxs = HWO - 1;
    const int ho = pxs / 190;
    const int wo = pxs - ho * 190;
    const float* offp = offs + (size_t)n * 36 * HWO;
    const unsigned short* xb = xt + (size_t)n * HWc * C1c;

    v4f acc[3];
    #pragma unroll
    for (int i = 0; i < 3; ++i) acc[i] = (v4f){0.f, 0.f, 0.f, 0.f};

    #pragma unroll 1
    for (int t = 0; t < 9; ++t) {
        const int ki = t / 3, kj = t - ki * 3;

        // ---- corner data for (pi, dgl) in lanes 0..31 (32..63 duplicate)
        float dy = offp[(size_t)(dgl * 18 + 2 * t + 0) * HWO + pxs];
        float dx = offp[(size_t)(dgl * 18 + 2 * t + 1) * HWO + pxs];
        float py  = (float)(ho + ki) + dy;
        float pxf = (float)(wo + kj) + dx;
        float fy0 = floorf(py), fx0 = floorf(pxf);
        float wy = py - fy0, wx = pxf - fx0;
        float fy1 = fy0 + 1.f, fx1 = fx0 + 1.f;
        bool vy0 = (fy0 >= 0.f) && (fy0 <= (float)(Hc - 1));
        bool vy1 = (fy1 >= 0.f) && (fy1 <= (float)(Hc - 1));
        bool vx0 = (fx0 >= 0.f) && (fx0 <= (float)(Wc - 1));
        bool vx1 = (fx1 >= 0.f) && (fx1 <= (float)(Wc - 1));
        int iy0 = min(max((int)fy0, 0), Hc - 1);
        int iy1 = min(max((int)fy1, 0), Hc - 1);
        int ix0 = min(max((int)fx0, 0), Wc - 1);
        int ix1 = min(max((int)fx1, 0), Wc - 1);
        float w00v = (vy0 && vx0) ? (1.f - wy) * (1.f - wx) : 0.f;
        float w01v = (vy0 && vx1) ? (1.f - wy) * wx         : 0.f;
        float w10v = (vy1 && vx0) ? wy * (1.f - wx)         : 0.f;
        float w11v = (vy1 && vx1) ? wy * wx                 : 0.f;
        int c00v = iy0 * Wc + ix0;
        int c01v = iy0 * Wc + ix1;
        int c10v = iy1 * Wc + ix0;
        int c11v = iy1 * Wc + ix1;

        // ---- sampling: 4 batches x 8 sample-rows; 32 loads in flight/batch
        #pragma unroll 1
        for (int grp = 0; grp < 4; ++grp) {
            int cof[8][4];
            #pragma unroll
            for (int u = 0; u < 8; ++u) {
                const int src = grp * 8 + u;
                cof[u][0] = __builtin_amdgcn_readlane(c00v, src);
                cof[u][1] = __builtin_amdgcn_readlane(c01v, src);
                cof[u][2] = __builtin_amdgcn_readlane(c10v, src);
                cof[u][3] = __builtin_amdgcn_readlane(c11v, src);
            }
            unsigned short raw[8][4];
            #pragma unroll
            for (int u = 0; u < 8; ++u) {
                const int src = grp * 8 + u;
                const unsigned short* bp = xb + (src >> 4) * 64 + lane;
                #pragma unroll
                for (int k = 0; k < 4; ++k)
                    raw[u][k] = bp[(size_t)cof[u][k] * C1c];
            }
            #pragma unroll
            for (int u = 0; u < 8; ++u) {
                const int src = grp * 8 + u;
                const int p = src & 15, dg = src >> 4;
                float w00 = rlanef(w00v, src);
                float w01 = rlanef(w01v, src);
                float w10 = rlanef(w10v, src);
                float w11 = rlanef(w11v, src);
                float v = fmaf(w11, bf2f(raw[u][3]),
                          fmaf(w10, bf2f(raw[u][2]),
                          fmaf(w01, bf2f(raw[u][1]), w00 * bf2f(raw[u][0]))));
                Sw[p * SPITCH + dg * 64 + lane] = f2bf(v);
            }
        }

        // ---- MFMA: D[o][px] += W_t[o][k] * S[k][px], K=128 in 4 steps
        const unsigned short* wt = wb + ((size_t)t * 48 + (lane & 15)) * C1c + ((lane >> 4) & 3) * 8;
        const unsigned short* sb = Sw + (lane & 15) * SPITCH + ((lane >> 4) & 3) * 8;
        #pragma unroll
        for (int ks = 0; ks < 4; ++ks) {
            v8s bfrag = *(const v8s*)(sb + ks * 32);
            v8s a0 = *(const v8s*)(wt + ks * 32);
            v8s a1 = *(const v8s*)(wt + 16 * C1c + ks * 32);
            v8s a2 = *(const v8s*)(wt + 32 * C1c + ks * 32);
            acc[0] = __builtin_amdgcn_mfma_f32_16x16x32_bf16(a0, bfrag, acc[0], 0, 0, 0);
            acc[1] = __builtin_amdgcn_mfma_f32_16x16x32_bf16(a1, bfrag, acc[1], 0, 0, 0);
            acc[2] = __builtin_amdgcn_mfma_f32_16x16x32_bf16(a2, bfrag, acc[2], 0, 0, 0);
        }
    }

    // ---- epilogue: BN + Mish; C layout col=lane&15 (px), row=quad*4+reg (o)
    const int col  = lane & 15;
    const int rowq = ((lane >> 4) & 3) * 4;
    const int pxo  = pxb + col;
    if (pxo < HWO) {
        #pragma unroll
        for (int ot = 0; ot < 3; ++ot) {
            #pragma unroll
            for (int r = 0; r < 4; ++r) {
                int o = ot * 16 + rowq + r;
                if (o < 36) {
                    float inv = bn_gamma[o] * rsqrtf(bn_var[o] + 1e-5f);
                    float b   = bn_beta[o] - bn_mean[o] * inv;
                    float v   = fmaf(acc[ot][r], inv, b);
                    float sp  = (v > 20.f) ? v : log1pf(__expf(v));
                    float e2  = __expf(-2.f * sp);
                    float th  = (1.f - e2) / (1.f + e2);
                    out[((size_t)n * 36 + o) * HWO + pxo] = v * th;
                }
            }
        }
    }
}

extern "C" void kernel_launch(void* const* d_in, const int* in_sizes, int n_in,
                              void* d_out, int out_size, void* d_ws, size_t ws_size,
                              hipStream_t stream) {
    (void)in_sizes; (void)n_in; (void)out_size; (void)ws_size;
    const float* x        = (const float*)d_in[0];
    const float* conv_w   = (const float*)d_in[1];
    const float* deform_w = (const float*)d_in[2];
    const float* bn_gamma = (const float*)d_in[3];
    const float* bn_beta  = (const float*)d_in[4];
    const float* bn_mean  = (const float*)d_in[5];
    const float* bn_var   = (const float*)d_in[6];
    float* out = (float*)d_out;

    float*          offs = (float*)d_ws;                                     // 20.8 MB
    unsigned short* xt   = (unsigned short*)(offs + (size_t)NN * 36 * HWO);  // 37.7 MB
    unsigned short* wbp  = xt + (size_t)NN * HWc * C1c;                      // 110.6 KB
    float*          cwT  = (float*)(wbp + (size_t)9 * 48 * 128);             // 43 KB

    x_to_nhwc<<<dim3(3, 192, 4), 256, 0, stream>>>(x, xt);
    w_prep<<<216, 256, 0, stream>>>(deform_w, wbp);
    cw_prep<<<42, 256, 0, stream>>>(conv_w, cwT);
    dcn_offsets<<<dim3(3, 48, 16), 256, 0, stream>>>(x, cwT, offs);
    dcn_mfma<<<dim3(8 * 283, 1), 256, 0, stream>>>(xt, wbp, offs,
                                                   bn_gamma, bn_beta, bn_mean, bn_var, out);
}

// Round 7
// 363.918 us; speedup vs baseline: 3.7686x; 1.2356x over previous
//
#include <hip/hip_runtime.h>
#include <hip/hip_bf16.h>
#include <math.h>

#define NN     4
#define C1c    128
#define C2c    36
#define Hc     192
#define Wc     192
#define HOc    190
#define WOc    190
#define HWc    (Hc*Wc)        // 36864
#define HWO    (HOc*WOc)      // 36100

using v8s = __attribute__((ext_vector_type(8))) short;
using v4i = __attribute__((ext_vector_type(4))) int;
using v4f = __attribute__((ext_vector_type(4))) float;

__device__ __forceinline__ unsigned short f2bf(float f) {
    __hip_bfloat16 h = __float2bfloat16(f);
    return __builtin_bit_cast(unsigned short, h);
}
__device__ __forceinline__ float bf2f(unsigned short u) {
    __hip_bfloat16 h = __builtin_bit_cast(__hip_bfloat16, u);
    return __bfloat162float(h);
}

// ---------------- x: NCHW fp32 -> NHWC bf16 ------------------------------
__global__ void x_to_nhwc(const float* __restrict__ x, unsigned short* __restrict__ xt) {
    __shared__ float tile[64 * 129];
    const int tid = threadIdx.x;
    const int w0  = blockIdx.x * 64;
    const int h   = blockIdx.y;
    const int n   = blockIdx.z;
    {
        const int w  = tid & 63, cb = tid >> 6;
        const float* xp = x + ((size_t)n * C1c * Hc + h) * Wc + w0 + w;
        #pragma unroll
        for (int i = 0; i < 32; ++i) {
            int c = cb + i * 4;
            tile[w * 129 + c] = xp[(size_t)c * HWc];
        }
    }
    __syncthreads();
    {
        const int c2 = tid & 127, wb2l = tid >> 7;
        unsigned short* op = xt + ((size_t)((n * Hc + h) * Wc) + w0) * C1c + c2;
        #pragma unroll
        for (int j = 0; j < 32; ++j) {
            int ww = wb2l + j * 2;
            op[(size_t)ww * C1c] = f2bf(tile[ww * 129 + c2]);
        }
    }
}

// ---------------- deform_w -> bf16 A-fragment layout (permuted K) ---------
// K permutation: k = s*32 + quad*8 + j  <->  channel c = (quad>>1)*64 + s*16 + (quad&1)*8 + j
// wb2[((tap*3 + oblk)*4 + s)*512 + lane*8 + j] = W[o = oblk*16 + (lane&15)][c]
__global__ void w_prep2(const float* __restrict__ dw, unsigned short* __restrict__ wb2) {
    int i = blockIdx.x * 256 + threadIdx.x;
    if (i >= 9 * 3 * 4 * 64 * 8) return;
    int j    = i & 7;
    int lane = (i >> 3) & 63;
    int s    = (i >> 9) & 3;
    int rem  = i >> 11;            // tap*3 + oblk
    int oblk = rem % 3;
    int tap  = rem / 3;
    int quad = (lane >> 4) & 3;
    int o = oblk * 16 + (lane & 15);
    int c = (quad >> 1) * 64 + s * 16 + (quad & 1) * 8 + j;
    float v = (o < 36) ? dw[((size_t)o * C1c + c) * 9 + tap] : 0.f;
    wb2[i] = f2bf(v);
}

// ---------------- conv_w -> cwT[(g*32+ci)*84 + oo*9+tt] (rows padded) -----
__global__ void cw_prep(const float* __restrict__ cw, float* __restrict__ cwT) {
    int i = blockIdx.x * 256 + threadIdx.x;
    if (i >= 4 * 32 * 84) return;
    int r   = i / 84;          // g*32+ci
    int idx = i - r * 84;
    int g = r >> 5, ci = r & 31;
    float v = 0.f;
    if (idx < 81) {
        int oo = idx / 9, tt = idx - oo * 9;
        int o  = g * 9 + oo;
        v = cw[(o * 32 + ci) * 9 + tt];
    }
    cwT[i] = v;
}

// ---------------- offset conv: interleaved (dy,dx) output -----------------
// offi[(((n*2+dg)*9 + t)*HWO + px)*2 + {0,1}] = (dy,dx)
__launch_bounds__(256, 8)
__global__ void dcn_offsets(const float* __restrict__ x,
                            const float* __restrict__ cwT,
                            float* __restrict__ offi) {
    const int tid = threadIdx.x;
    const int n   = blockIdx.z >> 2;
    const int g   = blockIdx.z & 3;
    int wo = blockIdx.x * 64 + (tid & 63);
    int ho = blockIdx.y * 4  + (tid >> 6);
    const bool active = (wo < WOc) && (ho < HOc);
    if (wo > WOc - 1) wo = WOc - 1;
    if (ho > HOc - 1) ho = HOc - 1;

    float offv[9];
    #pragma unroll
    for (int oo = 0; oo < 9; ++oo) offv[oo] = 0.f;

    const float* xp0 = x + ((size_t)n * C1c + g * 32) * HWc + ho * Wc + wo;
    const float* wr0 = cwT + (size_t)g * 32 * 84;
    #pragma unroll 1
    for (int ci = 0; ci < 32; ++ci) {
        const float* xp = xp0 + (size_t)ci * HWc;
        float xv[9];
        #pragma unroll
        for (int i = 0; i < 3; ++i)
            #pragma unroll
            for (int j = 0; j < 3; ++j)
                xv[i * 3 + j] = xp[i * Wc + j];
        const float* wr = wr0 + ci * 84;   // wave-uniform -> s_load
        #pragma unroll
        for (int oo = 0; oo < 9; ++oo) {
            float a = offv[oo];
            #pragma unroll
            for (int tt = 0; tt < 9; ++tt)
                a = fmaf(xv[tt], wr[oo * 9 + tt], a);
            offv[oo] = a;
        }
    }

    if (active) {
        const int px = ho * WOc + wo;
        float* base = offi + (size_t)n * 18 * HWO * 2;
        #pragma unroll
        for (int oo = 0; oo < 9; ++oo) {
            int og = g * 9 + oo;
            int dg = og / 18;
            int r  = og - dg * 18;
            int tt = r >> 1;
            int cc = r & 1;
            base[(((size_t)dg * 9 + tt) * HWO + px) * 2 + cc] = offv[oo];
        }
    }
}

// ---------------- main: LDS-free gather-to-fragment + MFMA + BN/Mish ------
__launch_bounds__(256, 4)
__global__ void dcn_mfma(const unsigned short* __restrict__ xt,
                         const unsigned short* __restrict__ wb2,
                         const float* __restrict__ offi,
                         const float* __restrict__ bn_gamma,
                         const float* __restrict__ bn_beta,
                         const float* __restrict__ bn_mean,
                         const float* __restrict__ bn_var,
                         float* __restrict__ out) {
    const int tid  = threadIdx.x;
    const int lane = tid & 63;
    const int wave = tid >> 6;

    // XCD-contiguous decode: each XCD owns 283 consecutive (n,strip) slots.
    int gs = (blockIdx.x & 7) * 283 + (blockIdx.x >> 3);
    if (gs > NN * 565 - 1) gs = NN * 565 - 1;
    const int n     = gs / 565;
    const int strip = gs - n * 565;
    const int pxb   = strip * 64 + wave * 16;

    const int pi    = lane & 15;        // px within wave tile
    const int dgl   = lane >> 5;        // deformable group (now consistent with perm K)
    const int qlow  = (lane >> 4) & 1;
    const int kgoff = dgl * 128 + qlow * 16;   // byte offset of this lane's channel base
    int pxs = pxb + pi;
    if (pxs > HWO - 1) pxs = HWO - 1;
    const int ho = pxs / 190;
    const int wo = pxs - ho * 190;

    const float* offp = offi + ((size_t)(n * 2 + dgl) * 9) * HWO * 2 + (size_t)pxs * 2;
    const char*  xbc  = (const char*)(xt + (size_t)n * HWc * C1c);

    v4f acc[3];
    #pragma unroll
    for (int i = 0; i < 3; ++i) acc[i] = (v4f){0.f, 0.f, 0.f, 0.f};

    #pragma unroll 1
    for (int t = 0; t < 9; ++t) {
        const int ki = t / 3, kj = t - ki * 3;

        // ---- per-lane corner math (every lane owns its (px, dg)) ----
        float2 d = *(const float2*)(offp + (size_t)t * HWO * 2);
        float py  = (float)(ho + ki) + d.x;
        float pxf = (float)(wo + kj) + d.y;
        float fy0 = floorf(py), fx0 = floorf(pxf);
        float wy = py - fy0, wx = pxf - fx0;
        float fy1 = fy0 + 1.f, fx1 = fx0 + 1.f;
        bool vy0 = (fy0 >= 0.f) && (fy0 <= (float)(Hc - 1));
        bool vy1 = (fy1 >= 0.f) && (fy1 <= (float)(Hc - 1));
        bool vx0 = (fx0 >= 0.f) && (fx0 <= (float)(Wc - 1));
        bool vx1 = (fx1 >= 0.f) && (fx1 <= (float)(Wc - 1));
        int iy0 = min(max((int)fy0, 0), Hc - 1);
        int iy1 = min(max((int)fy1, 0), Hc - 1);
        int ix0 = min(max((int)fx0, 0), Wc - 1);
        int ix1 = min(max((int)fx1, 0), Wc - 1);
        float w00 = (vy0 && vx0) ? (1.f - wy) * (1.f - wx) : 0.f;
        float w01 = (vy0 && vx1) ? (1.f - wy) * wx         : 0.f;
        float w10 = (vy1 && vx0) ? wy * (1.f - wx)         : 0.f;
        float w11 = (vy1 && vx1) ? wy * wx                 : 0.f;
        // byte offsets into NHWC bf16 image (256 B per spatial position)
        int va00 = (iy0 * Wc + ix0) * 256 + kgoff;
        int va01 = (iy0 * Wc + ix1) * 256 + kgoff;
        int va10 = (iy1 * Wc + ix0) * 256 + kgoff;
        int va11 = (iy1 * Wc + ix1) * 256 + kgoff;

        const unsigned short* wtap = wb2 + (size_t)t * 6144;  // 3 oblk * 4 s * 512

        #pragma unroll
        for (int s = 0; s < 4; ++s) {
            // 4 corner gathers: 8 channels (c = dgl*64 + s*16 + qlow*8 + j), B-frag order
            v8s q0 = *(const v8s*)(xbc + va00 + s * 32);
            v8s q1 = *(const v8s*)(xbc + va01 + s * 32);
            v8s q2 = *(const v8s*)(xbc + va10 + s * 32);
            v8s q3 = *(const v8s*)(xbc + va11 + s * 32);

            v4i bi;
            #pragma unroll
            for (int jj = 0; jj < 4; ++jj) {
                float v0 = fmaf(w11, bf2f((unsigned short)q3[2*jj]),
                           fmaf(w10, bf2f((unsigned short)q2[2*jj]),
                           fmaf(w01, bf2f((unsigned short)q1[2*jj]),
                                w00 * bf2f((unsigned short)q0[2*jj]))));
                float v1 = fmaf(w11, bf2f((unsigned short)q3[2*jj+1]),
                           fmaf(w10, bf2f((unsigned short)q2[2*jj+1]),
                           fmaf(w01, bf2f((unsigned short)q1[2*jj+1]),
                                w00 * bf2f((unsigned short)q0[2*jj+1]))));
                bi[jj] = (int)f2bf(v0) | ((int)f2bf(v1) << 16);
            }
            v8s bfrag = __builtin_bit_cast(v8s, bi);

            const v8s a0 = *(const v8s*)(wtap + (0 * 4 + s) * 512 + lane * 8);
            const v8s a1 = *(const v8s*)(wtap + (1 * 4 + s) * 512 + lane * 8);
            const v8s a2 = *(const v8s*)(wtap + (2 * 4 + s) * 512 + lane * 8);
            acc[0] = __builtin_amdgcn_mfma_f32_16x16x32_bf16(a0, bfrag, acc[0], 0, 0, 0);
            acc[1] = __builtin_amdgcn_mfma_f32_16x16x32_bf16(a1, bfrag, acc[1], 0, 0, 0);
            acc[2] = __builtin_amdgcn_mfma_f32_16x16x32_bf16(a2, bfrag, acc[2], 0, 0, 0);
        }
    }

    // ---- epilogue: BN + Mish; C layout col=lane&15 (px), row=quad*4+reg (o)
    const int col  = lane & 15;
    const int rowq = ((lane >> 4) & 3) * 4;
    const int pxo  = pxb + col;
    if (pxo < HWO) {
        #pragma unroll
        for (int ot = 0; ot < 3; ++ot) {
            #pragma unroll
            for (int r = 0; r < 4; ++r) {
                int o = ot * 16 + rowq + r;
                if (o < 36) {
                    float inv = bn_gamma[o] * rsqrtf(bn_var[o] + 1e-5f);
                    float b   = bn_beta[o] - bn_mean[o] * inv;
                    float v   = fmaf(acc[ot][r], inv, b);
                    float sp  = (v > 20.f) ? v : log1pf(__expf(v));
                    float e2  = __expf(-2.f * sp);
                    float th  = (1.f - e2) / (1.f + e2);
                    out[((size_t)n * 36 + o) * HWO + pxo] = v * th;
                }
            }
        }
    }
}

extern "C" void kernel_launch(void* const* d_in, const int* in_sizes, int n_in,
                              void* d_out, int out_size, void* d_ws, size_t ws_size,
                              hipStream_t stream) {
    (void)in_sizes; (void)n_in; (void)out_size; (void)ws_size;
    const float* x        = (const float*)d_in[0];
    const float* conv_w   = (const float*)d_in[1];
    const float* deform_w = (const float*)d_in[2];
    const float* bn_gamma = (const float*)d_in[3];
    const float* bn_beta  = (const float*)d_in[4];
    const float* bn_mean  = (const float*)d_in[5];
    const float* bn_var   = (const float*)d_in[6];
    float* out = (float*)d_out;

    float*          offi = (float*)d_ws;                                     // 20.8 MB
    unsigned short* xt   = (unsigned short*)(offi + (size_t)NN * 36 * HWO);  // 37.7 MB
    unsigned short* wbp2 = xt + (size_t)NN * HWc * C1c;                      // 110.6 KB
    float*          cwT  = (float*)(wbp2 + (size_t)9 * 3 * 4 * 64 * 8);      // 43 KB

    x_to_nhwc<<<dim3(3, 192, 4), 256, 0, stream>>>(x, xt);
    w_prep2<<<216, 256, 0, stream>>>(deform_w, wbp2);
    cw_prep<<<42, 256, 0, stream>>>(conv_w, cwT);
    dcn_offsets<<<dim3(3, 48, 16), 256, 0, stream>>>(x, cwT, offi);
    dcn_mfma<<<dim3(8 * 283, 1), 256, 0, stream>>>(xt, wbp2, offi,
                                                   bn_gamma, bn_beta, bn_mean, bn_var, out);
}